// Round 6
// baseline (232.976 us; speedup 1.0000x reference)
//
#include <hip/hip_runtime.h>
#include <hip/hip_bf16.h>

// KPConv round 6: exact 32-slot compaction + halved-F two-round phase A/B.
// Phase A (per q, per c-half): f[k16, c64] = infl[k16, slot32] @ feat[slot32, c64]
//   one 16x16x32 bf16 MFMA per (q, c-tile); feat gathered per-lane from global,
//   predicated by slot<cnt (glist zero-init => safe addresses). Exact for any cnt<=32.
// f LDS layout (per half, c' = c - 64r, ck' = c'*16+k):
//   kt'=ck'>>5, lgB=(ck'&31)>>3, j=ck'&7; byte = kt'*1024+lgB*256+q*16+j*2,
//   byte ^= ((c'&7)<<4).  Phase-B A-read = lane-contiguous 16B (conflict-free);
//   phase-A D-write = 4-way b64. Swizzle: write s=c'&7 == read s=(lg>>1)|((kt'&3)<<1).
// Phase B: out[16q x 128o] = f[16 x 2048] @ W'[2048 x 128], accumulated across the
//   two rounds in registers; W' in d_ws as wfrag[nt][kt][lane] uint4.

typedef short bf16x8 __attribute__((ext_vector_type(8)));
typedef float f32x4 __attribute__((ext_vector_type(4)));

constexpr int Qn = 20000;
constexpr int Hn = 32;
constexpr int Kn = 15;
constexpr int Cn = 128;
constexpr int On = 128;
constexpr int QB = 16;
constexpr int BLOCK = 512;

// LDS pool byte offsets. F region [0, 32768); staging aliases its head (dead by P4).
constexpr int F_OFF     = 0;
constexpr int NPT_OFF   = 0;        // f32 [512][4]            8192
constexpr int DENSE_OFF = 8192;     // bf16 [16][32h][16k]    16384
constexpr int NIDX_OFF  = 24576;    // int [512]               2048
constexpr int HLIST_OFF = 26624;    // i16 [16][32]            1024
constexpr int QPL_OFF   = 27648;    // f32 [16][4]              256
constexpr int KPL_OFF   = 27904;    // f32 [16][4]              256
constexpr int FLG_OFF   = 28160;    // u32 [16]                  64
// persistent (live through P4/P5):
constexpr int INFL_OFF  = 32768;    // bf16 [16][16k][32slot], swz ^((k&7)<<4)  16384
constexpr int GLIST_OFF = 49152;    // int  [16][32]            2048
constexpr int CNT_OFF   = 51200;    // int  [16]                  64
constexpr int POOL_SZ   = 51264;    // ~51.3 KB -> 2+ blocks/CU

__device__ __forceinline__ unsigned short bfu(float x) {
  union { __hip_bfloat16 h; unsigned short s; } cv;
  cv.h = __float2bfloat16(x);
  return cv.s;
}
__device__ __forceinline__ unsigned pk2(float a, float b) {
  union { __hip_bfloat162 h2; unsigned u; } cv;
  cv.h2 = __float22bfloat162_rn(make_float2(a, b));
  return cv.u;
}

// ---- W -> bf16 B-fragment layout wfrag[nt][kt][lane][4 words]
// uint tid = ((nt*64 + kt)*64 + l)*4 + wsel; holds W'[ck],W'[ck+1] at
// col = nt*16 + (l&15), ck = kt*32 + (l>>4)*8 + wsel*2, W'[c*16+k] = wts[k][c][col].
__global__ void conv_w(const float* __restrict__ wts, unsigned* __restrict__ wfrag) {
  int tid = blockIdx.x * 256 + threadIdx.x;     // 131072 threads
  int wsel = tid & 3;
  int l    = (tid >> 2) & 63;
  int kt   = (tid >> 8) & 63;
  int nt   = tid >> 14;
  int col  = nt * 16 + (l & 15);
  int ck   = kt * 32 + (l >> 4) * 8 + wsel * 2;
  int k0 = ck & 15, c0 = ck >> 4;               // k0 even <= 14
  int k1 = k0 + 1;
  float a = wts[(k0 * Cn + c0) * On + col];
  float b = (k1 < Kn) ? wts[(k1 * Cn + c0) * On + col] : 0.f;
  wfrag[tid] = pk2(a, b);
}

__global__ __launch_bounds__(BLOCK, 4)
void kpconv_main(const float* __restrict__ qpts,
                 const float* __restrict__ sfeat,
                 const float* __restrict__ kpts,
                 const int* __restrict__ nidx,
                 const unsigned* __restrict__ wfrag,
                 float* __restrict__ out) {
  __shared__ __align__(16) char pool[POOL_SZ];
  const int t = threadIdx.x;
  const int qbase = blockIdx.x * QB;
  const int l = t & 63, w = t >> 6;
  const int lg = l >> 4, li = l & 15;

  // ---------------- P0: stage points/indices, zero glist/flags
  {
    *(unsigned*)(pool + GLIST_OFF + t * 4) = 0u;          // all 512 entries
    int g = nidx[(size_t)qbase * Hn + t];                 // t = q*32+h
    *(int*)(pool + NIDX_OFF + t * 4) = g;
    float* np = (float*)(pool + NPT_OFF + t * 16);
    np[0] = qpts[g * 3 + 0];
    np[1] = qpts[g * 3 + 1];
    np[2] = qpts[g * 3 + 2];
    if (t < 16) {
      *(unsigned*)(pool + FLG_OFF + t * 4) = 0u;
      float* qp = (float*)(pool + QPL_OFF + t * 16);
      qp[0] = qpts[(qbase + t) * 3 + 0];
      qp[1] = qpts[(qbase + t) * 3 + 1];
      qp[2] = qpts[(qbase + t) * 3 + 2];
    }
    if (t >= 32 && t < 32 + Kn) {
      int k = t - 32;
      float* kp = (float*)(pool + KPL_OFF + k * 16);
      kp[0] = kpts[k * 3 + 0];
      kp[1] = kpts[k * 3 + 1];
      kp[2] = kpts[k * 3 + 2];
    }
  }
  __syncthreads();

  // ---------------- P1: dense influences -> DENSE + activity flags
#pragma unroll
  for (int it = 0; it < 16; ++it) {
    int idx = t + it * BLOCK;            // [q][h][k16]
    int k = idx & 15, h = (idx >> 4) & 31, q = idx >> 9;
    unsigned short v = 0;
    if (k < Kn) {
      const float* np = (const float*)(pool + NPT_OFF + (q * 32 + h) * 16);
      const float* qp = (const float*)(pool + QPL_OFF + q * 16);
      const float* kp = (const float*)(pool + KPL_OFF + k * 16);
      float dx = np[0] - qp[0] - kp[0];
      float dy = np[1] - qp[1] - kp[1];
      float dz = np[2] - qp[2] - kp[2];
      float d = sqrtf(dx * dx + dy * dy + dz * dz);
      float inf = fmaxf(0.f, 1.f - d);
      if (inf > 0.f) atomicOr((unsigned*)(pool + FLG_OFF) + q, 1u << h);
      v = bfu(inf);
    }
    *(unsigned short*)(pool + DENSE_OFF + q * 1024 + h * 32 + k * 2) = v;
  }
  __syncthreads();

  // ---------------- P2: compact active-h lists
  if (t < 16) {
    unsigned m = *(unsigned*)(pool + FLG_OFF + t * 4);
    *(int*)(pool + CNT_OFF + t * 4) = __popc(m);
    int i = 0;
    while (m) {
      int h = __ffs(m) - 1; m &= m - 1;
      *(short*)(pool + HLIST_OFF + t * 64 + i * 2) = (short)h;
      *(int*)(pool + GLIST_OFF + t * 128 + i * 4) =
          *(const int*)(pool + NIDX_OFF + (t * 32 + h) * 4);
      ++i;
    }
  }
  __syncthreads();

  // ---------------- P3: scatter into A-frag layout infl[q][k16][slot32] (swz k)
#pragma unroll
  for (int it = 0; it < 16; ++it) {
    int idx = t + it * BLOCK;            // [q][k16][slot32]
    int slot = idx & 31, k = (idx >> 5) & 15, q = idx >> 9;
    int cnt = *(const int*)(pool + CNT_OFF + q * 4);
    unsigned short v = 0;
    if (k < Kn && slot < cnt) {
      int h = *(const short*)(pool + HLIST_OFF + q * 64 + slot * 2);
      v = *(const unsigned short*)(pool + DENSE_OFF + q * 1024 + h * 32 + k * 2);
    }
    unsigned byte = (unsigned)(q * 1024) +
        (((unsigned)(k * 64 + slot * 2)) ^ (((unsigned)k & 7u) << 4));
    *(unsigned short*)(pool + INFL_OFF + byte) = v;
  }
  __syncthreads();   // staging aliases dead; F writable

  // ---------------- P4/P5 fused, two c-half rounds; phase-B acc in registers
  const int ctl = w & 3, qg = w >> 2;           // wave -> (c-tile, q-group)
  const unsigned abase0 = (unsigned)INFL_OFF +
      (((unsigned)(li * 64 + lg * 16)) ^ (((unsigned)li & 7u) << 4));
  const int cl = ctl * 16 + li;                  // c' local in [0,64)
  const unsigned wswz = ((unsigned)cl & 7u) << 4;
  const unsigned wbase0 = (unsigned)((cl >> 1) * 1024 +
                                     ((cl & 1) * 2 + (lg >> 1)) * 256 +
                                     (lg & 1) * 8);
  const unsigned liB = (unsigned)(lg * 256 + li * 16);
  const unsigned sLg = ((unsigned)(lg >> 1)) << 4;
  const uint4* wfp = (const uint4*)wfrag + (size_t)w * 4096 + l;
  f32x4 acc0 = {0.f, 0.f, 0.f, 0.f}, acc1 = {0.f, 0.f, 0.f, 0.f};

#pragma unroll 1
  for (int r = 0; r < 2; ++r) {
    const int cbase = r * 64 + cl;               // global c this lane gathers
    // ---- phase-A MFMA for this half: 8 q's per wave
#pragma unroll 2
    for (int qi = 0; qi < 8; ++qi) {
      const int q = qg * 8 + qi;
      int cnt = *(const int*)(pool + CNT_OFF + q * 4);
      bf16x8 afrag = *(const bf16x8*)(pool + abase0 + q * 1024);
      uint4 ga = *(const uint4*)(pool + GLIST_OFF + q * 128 + lg * 32);
      uint4 gb = *(const uint4*)(pool + GLIST_OFF + q * 128 + lg * 32 + 16);
      int s0 = lg * 8;
      float v0 = (s0 + 0 < cnt) ? sfeat[(size_t)ga.x * Cn + cbase] : 0.f;
      float v1 = (s0 + 1 < cnt) ? sfeat[(size_t)ga.y * Cn + cbase] : 0.f;
      float v2 = (s0 + 2 < cnt) ? sfeat[(size_t)ga.z * Cn + cbase] : 0.f;
      float v3 = (s0 + 3 < cnt) ? sfeat[(size_t)ga.w * Cn + cbase] : 0.f;
      float v4 = (s0 + 4 < cnt) ? sfeat[(size_t)gb.x * Cn + cbase] : 0.f;
      float v5 = (s0 + 5 < cnt) ? sfeat[(size_t)gb.y * Cn + cbase] : 0.f;
      float v6 = (s0 + 6 < cnt) ? sfeat[(size_t)gb.z * Cn + cbase] : 0.f;
      float v7 = (s0 + 7 < cnt) ? sfeat[(size_t)gb.w * Cn + cbase] : 0.f;
      uint4 bu;
      bu.x = pk2(v0, v1); bu.y = pk2(v2, v3);
      bu.z = pk2(v4, v5); bu.w = pk2(v6, v7);
      bf16x8 bfrag = *(bf16x8*)&bu;
      f32x4 z = {0.f, 0.f, 0.f, 0.f};
      f32x4 d = __builtin_amdgcn_mfma_f32_16x16x32_bf16(afrag, bfrag, z, 0, 0, 0);
      // D row k = lg*4+rr, col c' = cl -> f[q][c'*16+k], 4 consecutive shorts
      unsigned byte = (wbase0 + (unsigned)(q * 16)) ^ wswz;
      *(uint2*)(pool + byte) = make_uint2(pk2(d[0], d[1]), pk2(d[2], d[3]));
    }
    __syncthreads();   // f half ready

    // ---- phase-B partial: wave w = N-tile w, kt' in [0,32)
    const int ktbase = r * 32;
#pragma unroll
    for (int kt = 0; kt < 32; kt += 2) {
      unsigned a0 = ((unsigned)(kt << 10) + liB) ^ (sLg | (((unsigned)kt & 3u) << 5));
      unsigned a1 = ((unsigned)((kt + 1) << 10) + liB) ^ (sLg | (((unsigned)(kt + 1) & 3u) << 5));
      bf16x8 f0 = *(const bf16x8*)(pool + a0);
      uint4 w0 = wfp[(size_t)(ktbase + kt) * 64];
      bf16x8 f1 = *(const bf16x8*)(pool + a1);
      uint4 w1 = wfp[(size_t)(ktbase + kt + 1) * 64];
      acc0 = __builtin_amdgcn_mfma_f32_16x16x32_bf16(f0, *(bf16x8*)&w0, acc0, 0, 0, 0);
      acc1 = __builtin_amdgcn_mfma_f32_16x16x32_bf16(f1, *(bf16x8*)&w1, acc1, 0, 0, 0);
    }
    __syncthreads();   // F consumed; next round may overwrite
  }

  // ---------------- epilogue: D row q = lg*4+rr, col o = w*16+li
  {
    f32x4 acc = acc0 + acc1;
    float* ob = out + (size_t)qbase * On + w * 16 + li;
#pragma unroll
    for (int rr = 0; rr < 4; ++rr)
      ob[(lg * 4 + rr) * On] = acc[rr];
  }
}

extern "C" void kernel_launch(void* const* d_in, const int* in_sizes, int n_in,
                              void* d_out, int out_size, void* d_ws, size_t ws_size,
                              hipStream_t stream) {
  const float* qpts  = (const float*)d_in[0];  // query_points [Q,3]
  const float* sfeat = (const float*)d_in[2];  // support_features [G,C]
  const float* kpts  = (const float*)d_in[3];  // kernel [K,3]
  const float* wts   = (const float*)d_in[4];  // weights [K,C,O]
  const int*   nidx  = (const int*)d_in[5];    // neighbor_indices [Q,H]
  float* outp = (float*)d_out;
  unsigned* wfrag = (unsigned*)d_ws;           // 524288 B needed

  conv_w<<<512, 256, 0, stream>>>(wts, wfrag);
  kpconv_main<<<Qn / QB, BLOCK, 0, stream>>>(qpts, sfeat, kpts, nidx, wfrag, outp);
}

// Round 8
// 223.819 us; speedup vs baseline: 1.0409x; 1.0409x over previous
//
#include <hip/hip_runtime.h>
#include <hip/hip_bf16.h>

// KPConv round 8: round-7 structure with the NaN bug fixed.
// BUG WAS: glist sentinel 0xFFFF == bf16 NaN; row 15 of the phase-A A-fragment
// enters the MFMA (D row 15), NaN*0=NaN -> f row15 NaN -> phase B NaN*W'(=0)=NaN.
// FIX: sentinel = 20000 (0x4E20, finite bf16); all indices <20000 are finite bf16.
//
// Phase A (per q): f[k16, c128] = infl[k16, slot32] @ feat[slot32, c128], one
//   16x16x32 bf16 MFMA per (q, c-tile); feat gathered per-lane from global.
//   Gather indices stored as u16 in INFL row k=15 (feeds only D row 15, which
//   phase B multiplies by W'[.,k=15]=0 -> finite don't-care). 20000 = inactive.
// f LDS layout (ck = c*16+k): byte = (c>>1)*1024 + ((c&1)*2+(k>>3))*256 + q*16
//   + (k&7)*2, then ^= ((c&7)<<4).  Phase-B A-read = lane-contiguous 16B
//   (conflict-free); phase-A D-write = 4-way b64. Bijective (verified algebra).
// Phase B: out[16q x 128o] = f[16 x 2048] @ W'[2048 x 128]; W' in d_ws as
//   wfrag[nt][kt][lane] uint4 (64KB contiguous stream per wave).
// LDS: F 64K + INFL 16K = 81920 B exactly -> 2 blocks/CU. Staging aliases F head.

typedef short bf16x8 __attribute__((ext_vector_type(8)));
typedef float f32x4 __attribute__((ext_vector_type(4)));

constexpr int Qn = 20000;
constexpr int Hn = 32;
constexpr int Kn = 15;
constexpr int Cn = 128;
constexpr int On = 128;
constexpr int QB = 16;
constexpr int KT = 64;
constexpr int BLOCK = 512;
constexpr unsigned SENT = 20000u;   // finite-bf16 sentinel (0x4E20); valid g < 20000

constexpr int F_OFF     = 0;        // 65536
constexpr int INFL_OFF  = 65536;    // bf16 [16][16k][32slot], swz ^((k&7)<<4); row15 = glist u16
constexpr int POOL_SZ   = 81920;    // exactly 2 blocks/CU
// staging aliases inside F (all dead before P4 writes F):
constexpr int NPT_OFF   = 0;        // f32 [512][4]            8192
constexpr int DENSE_OFF = 8192;     // bf16 [16][32h][16k]    16384
constexpr int NIDX_OFF  = 24576;    // int [512]               2048
constexpr int HLIST_OFF = 26624;    // i16 [16][32]            1024
constexpr int QPL_OFF   = 27648;    // f32 [16][4]              256
constexpr int KPL_OFF   = 27904;    // f32 [16][4]              256
constexpr int FLG_OFF   = 28160;    // u32 [16]                  64
constexpr int CNT_OFF   = 28224;    // int [16]                  64

__device__ __forceinline__ unsigned short bfu(float x) {
  union { __hip_bfloat16 h; unsigned short s; } cv;
  cv.h = __float2bfloat16(x);
  return cv.s;
}
__device__ __forceinline__ unsigned pk2(float a, float b) {
  union { __hip_bfloat162 h2; unsigned u; } cv;
  cv.h2 = __float22bfloat162_rn(make_float2(a, b));
  return cv.u;
}

// ---- W -> bf16 B-fragment layout wfrag[nt][kt][lane][4 words] (verified round 6)
__global__ void conv_w(const float* __restrict__ wts, unsigned* __restrict__ wfrag) {
  int tid = blockIdx.x * 256 + threadIdx.x;     // 131072 threads
  int wsel = tid & 3;
  int l    = (tid >> 2) & 63;
  int kt   = (tid >> 8) & 63;
  int nt   = tid >> 14;
  int col  = nt * 16 + (l & 15);
  int ck   = kt * 32 + (l >> 4) * 8 + wsel * 2;
  int k0 = ck & 15, c0 = ck >> 4;               // k0 even <= 14
  int k1 = k0 + 1;
  float a = wts[(k0 * Cn + c0) * On + col];
  float b = (k1 < Kn) ? wts[(k1 * Cn + c0) * On + col] : 0.f;
  wfrag[tid] = pk2(a, b);
}

__global__ __launch_bounds__(BLOCK, 4)
void kpconv_main(const float* __restrict__ qpts,
                 const float* __restrict__ sfeat,
                 const float* __restrict__ kpts,
                 const int* __restrict__ nidx,
                 const unsigned* __restrict__ wfrag,
                 float* __restrict__ out) {
  __shared__ __align__(16) char pool[POOL_SZ];
  const int t = threadIdx.x;
  const int qbase = blockIdx.x * QB;
  const int l = t & 63, w = t >> 6;
  const int lg = l >> 4, li = l & 15;

  // ---------------- P0: stage points/indices
  {
    int g = nidx[(size_t)qbase * Hn + t];                 // t = q*32+h
    *(int*)(pool + NIDX_OFF + t * 4) = g;
    float* np = (float*)(pool + NPT_OFF + t * 16);
    np[0] = qpts[g * 3 + 0];
    np[1] = qpts[g * 3 + 1];
    np[2] = qpts[g * 3 + 2];
    if (t < 16) {
      *(unsigned*)(pool + FLG_OFF + t * 4) = 0u;
      float* qp = (float*)(pool + QPL_OFF + t * 16);
      qp[0] = qpts[(qbase + t) * 3 + 0];
      qp[1] = qpts[(qbase + t) * 3 + 1];
      qp[2] = qpts[(qbase + t) * 3 + 2];
    }
    if (t >= 32 && t < 32 + Kn) {
      int k = t - 32;
      float* kp = (float*)(pool + KPL_OFF + k * 16);
      kp[0] = kpts[k * 3 + 0];
      kp[1] = kpts[k * 3 + 1];
      kp[2] = kpts[k * 3 + 2];
    }
  }
  __syncthreads();

  // ---------------- P1: dense influences -> DENSE + activity flags
#pragma unroll
  for (int it = 0; it < 16; ++it) {
    int idx = t + it * BLOCK;            // [q][h][k16]
    int k = idx & 15, h = (idx >> 4) & 31, q = idx >> 9;
    unsigned short v = 0;
    if (k < Kn) {
      const float* np = (const float*)(pool + NPT_OFF + (q * 32 + h) * 16);
      const float* qp = (const float*)(pool + QPL_OFF + q * 16);
      const float* kp = (const float*)(pool + KPL_OFF + k * 16);
      float dx = np[0] - qp[0] - kp[0];
      float dy = np[1] - qp[1] - kp[1];
      float dz = np[2] - qp[2] - kp[2];
      float d = sqrtf(dx * dx + dy * dy + dz * dz);
      float inf = fmaxf(0.f, 1.f - d);
      if (inf > 0.f) atomicOr((unsigned*)(pool + FLG_OFF) + q, 1u << h);
      v = bfu(inf);
    }
    *(unsigned short*)(pool + DENSE_OFF + q * 1024 + h * 32 + k * 2) = v;
  }
  __syncthreads();

  // ---------------- P2: compact active-h lists
  if (t < 16) {
    unsigned m = *(unsigned*)(pool + FLG_OFF + t * 4);
    *(int*)(pool + CNT_OFF + t * 4) = __popc(m);
    int i = 0;
    while (m) {
      int h = __ffs(m) - 1; m &= m - 1;
      *(short*)(pool + HLIST_OFF + t * 64 + i * 2) = (short)h;
      ++i;
    }
  }
  __syncthreads();

  // ---------------- P3: scatter into INFL[q][k16][slot32] (swz ^((k&7)<<4));
  //                  row k=15 carries the compacted gather index (u16, SENT=off)
#pragma unroll
  for (int it = 0; it < 16; ++it) {
    int idx = t + it * BLOCK;            // [q][k16][slot32]
    int slot = idx & 31, k = (idx >> 5) & 15, q = idx >> 9;
    int cnt = *(const int*)(pool + CNT_OFF + q * 4);
    unsigned short v;
    if (k == 15) {
      v = (unsigned short)SENT;          // finite bf16; D row15 is don't-care
      if (slot < cnt) {
        int h = *(const short*)(pool + HLIST_OFF + q * 64 + slot * 2);
        v = (unsigned short)(*(const int*)(pool + NIDX_OFF + (q * 32 + h) * 4));
      }
    } else {
      v = 0;
      if (slot < cnt) {
        int h = *(const short*)(pool + HLIST_OFF + q * 64 + slot * 2);
        v = *(const unsigned short*)(pool + DENSE_OFF + q * 1024 + h * 32 + k * 2);
      }
    }
    unsigned byte = (unsigned)(q * 1024) +
        (((unsigned)(k * 64 + slot * 2)) ^ (((unsigned)k & 7u) << 4));
    *(unsigned short*)(pool + INFL_OFF + byte) = v;
  }
  __syncthreads();   // staging dead; F writable

  // ---------------- P4: phase-A MFMA. wave w -> c-tile w, loop 16 q
  {
    const int c = w * 16 + li;
    const unsigned abase0 = (unsigned)INFL_OFF +
        (((unsigned)(li * 64 + lg * 16)) ^ (((unsigned)li & 7u) << 4));
    const unsigned glof = (unsigned)INFL_OFF +
        (((unsigned)(15 * 64 + lg * 16)) ^ 0x70u);
    const unsigned wswz = ((unsigned)c & 7u) << 4;
    const unsigned wbase0 = (unsigned)((c >> 1) * 1024 +
                                       ((c & 1) * 2 + (lg >> 1)) * 256 +
                                       (lg & 1) * 8);
#pragma unroll 2
    for (int q = 0; q < QB; ++q) {
      bf16x8 afrag = *(const bf16x8*)(pool + abase0 + q * 1024);
      uint4 gl = *(const uint4*)(pool + glof + q * 1024);
      unsigned g0 = gl.x & 0xFFFFu, g1 = gl.x >> 16;
      unsigned g2 = gl.y & 0xFFFFu, g3 = gl.y >> 16;
      unsigned g4 = gl.z & 0xFFFFu, g5 = gl.z >> 16;
      unsigned g6 = gl.w & 0xFFFFu, g7 = gl.w >> 16;
      float v0 = (g0 < SENT) ? sfeat[(size_t)g0 * Cn + c] : 0.f;
      float v1 = (g1 < SENT) ? sfeat[(size_t)g1 * Cn + c] : 0.f;
      float v2 = (g2 < SENT) ? sfeat[(size_t)g2 * Cn + c] : 0.f;
      float v3 = (g3 < SENT) ? sfeat[(size_t)g3 * Cn + c] : 0.f;
      float v4 = (g4 < SENT) ? sfeat[(size_t)g4 * Cn + c] : 0.f;
      float v5 = (g5 < SENT) ? sfeat[(size_t)g5 * Cn + c] : 0.f;
      float v6 = (g6 < SENT) ? sfeat[(size_t)g6 * Cn + c] : 0.f;
      float v7 = (g7 < SENT) ? sfeat[(size_t)g7 * Cn + c] : 0.f;
      uint4 bu;
      bu.x = pk2(v0, v1); bu.y = pk2(v2, v3);
      bu.z = pk2(v4, v5); bu.w = pk2(v6, v7);
      bf16x8 bfrag = *(bf16x8*)&bu;
      f32x4 z = {0.f, 0.f, 0.f, 0.f};
      f32x4 d = __builtin_amdgcn_mfma_f32_16x16x32_bf16(afrag, bfrag, z, 0, 0, 0);
      // D row k = lg*4+rr, col c -> f[q][c*16+k], 4 consecutive shorts
      unsigned byte = (wbase0 + (unsigned)(q * 16)) ^ wswz;
      *(uint2*)(pool + byte) = make_uint2(pk2(d[0], d[1]), pk2(d[2], d[3]));
    }
  }
  __syncthreads();

  // ---------------- P5: phase-B MFMA. wave w -> N-tile w, full kt sweep
  {
    const unsigned liB = (unsigned)(lg * 256 + li * 16);
    const unsigned sLg = ((unsigned)(lg >> 1)) << 4;
    const uint4* wfp = (const uint4*)wfrag + (size_t)w * 4096 + l;
    f32x4 acc0 = {0.f, 0.f, 0.f, 0.f}, acc1 = {0.f, 0.f, 0.f, 0.f};
#pragma unroll 8
    for (int kt = 0; kt < KT; kt += 2) {
      unsigned a0 = ((unsigned)(kt << 10) + liB) ^ (sLg | (((unsigned)kt & 3u) << 5));
      unsigned a1 = ((unsigned)((kt + 1) << 10) + liB) ^ (sLg | (((unsigned)(kt + 1) & 3u) << 5));
      bf16x8 f0 = *(const bf16x8*)(pool + a0);
      uint4 w0 = wfp[(size_t)kt * 64];
      bf16x8 f1 = *(const bf16x8*)(pool + a1);
      uint4 w1 = wfp[(size_t)(kt + 1) * 64];
      acc0 = __builtin_amdgcn_mfma_f32_16x16x32_bf16(f0, *(bf16x8*)&w0, acc0, 0, 0, 0);
      acc1 = __builtin_amdgcn_mfma_f32_16x16x32_bf16(f1, *(bf16x8*)&w1, acc1, 0, 0, 0);
    }
    f32x4 acc = acc0 + acc1;
    float* ob = out + (size_t)qbase * On + w * 16 + li;
#pragma unroll
    for (int rr = 0; rr < 4; ++rr)
      ob[(lg * 4 + rr) * On] = acc[rr];
  }
}

extern "C" void kernel_launch(void* const* d_in, const int* in_sizes, int n_in,
                              void* d_out, int out_size, void* d_ws, size_t ws_size,
                              hipStream_t stream) {
  const float* qpts  = (const float*)d_in[0];  // query_points [Q,3]
  const float* sfeat = (const float*)d_in[2];  // support_features [G,C]
  const float* kpts  = (const float*)d_in[3];  // kernel [K,3]
  const float* wts   = (const float*)d_in[4];  // weights [K,C,O]
  const int*   nidx  = (const int*)d_in[5];    // neighbor_indices [Q,H]
  float* outp = (float*)d_out;
  unsigned* wfrag = (unsigned*)d_ws;           // 524288 B needed

  conv_w<<<512, 256, 0, stream>>>(wts, wfrag);
  kpconv_main<<<Qn / QB, BLOCK, 0, stream>>>(qpts, sfeat, kpts, nidx, wfrag, outp);
}